// Round 9
// baseline (396.937 us; speedup 1.0000x reference)
//
#include <hip/hip_runtime.h>
#include <hip/hip_bf16.h>

// Bahdanau additive attention, B=32, L=2048, H=1024, fp32 in/out.
// score_kernel v4: 256-thr blocks (4 waves), wave tile 64l x 64o (acc[2][2]=64 AGPR),
// block tile 128l x 128o, __launch_bounds__(256,3) -> target 3 blocks/CU (12 waves).
// A (key) LDS double-buffered K=64 chunks (2x16KB), issue-early/write-late into dead
// buffer, ONE barrier/chunk. B (Ua) depth-3 register prefetch from L2 ([s][nb] layout).
// 8 oh-siblings per key tile share d%8 -> same XCD for L2 reuse.

#define B_ 32
#define L_ 2048
#define H_ 1024

typedef __attribute__((ext_vector_type(8))) short bf16x8;   // 8 bf16 = 4 VGPRs
typedef __attribute__((ext_vector_type(16))) float f32x16;  // 32x32 MFMA acc
typedef __attribute__((ext_vector_type(4))) float f32x4;

__device__ inline unsigned pk_bf16(float a, float b) {
    unsigned r;
    asm("v_cvt_pk_bf16_f32 %0, %1, %2" : "=v"(r) : "v"(a), "v"(b));
    return r;
}

__device__ inline float fast_tanh(float x) {
    float e = __expf(2.f * x);
    return 1.f - 2.f * __builtin_amdgcn_rcpf(e + 1.f);
}

// ---- kernel 0a: Ua_w -> bf16 B-fragments [s 0..63][nb 0..31][lane][j 0..7]
// lane l holds B[k=(l>>5)*8+j][col=nb*32+(l&31)], h = s*16+k.
__global__ void prep_ua(const float* __restrict__ Ua, ushort* __restrict__ Ufrag) {
    int t = blockIdx.x * 256 + threadIdx.x;   // 131072 slots of 8 ushort
    int lane = t & 63;
    int nb   = (t >> 6) & 31;
    int s    = t >> 11;
    int o = nb * 32 + (lane & 31);
    int h = s * 16 + (lane >> 5) * 8;
    const float* src = Ua + o * H_ + h;
    f32x4 f0 = *(const f32x4*)(src);
    f32x4 f1 = *(const f32x4*)(src + 4);
    uint4 pk;
    pk.x = pk_bf16(f0.x, f0.y);
    pk.y = pk_bf16(f0.z, f0.w);
    pk.z = pk_bf16(f1.x, f1.y);
    pk.w = pk_bf16(f1.z, f1.w);
    *(uint4*)(Ufrag + (size_t)t * 8) = pk;
}

// ---- kernel 0b: qbuf[b][o] = query[b]·Wa_w[o] + Wa_b[o] + Ua_b[o]
__global__ void prep_q(const float* __restrict__ query, const float* __restrict__ Wa_w,
                       const float* __restrict__ Wa_b, const float* __restrict__ Ua_b,
                       float* __restrict__ qbuf) {
    int wid  = blockIdx.x * 4 + (threadIdx.x >> 6);
    int lane = threadIdx.x & 63;
    int b = wid >> 10, o = wid & 1023;
    const float* qrow = query + b * H_;
    const float* wrow = Wa_w + o * H_;
    float acc = 0.f;
    #pragma unroll
    for (int i = 0; i < 16; ++i) {
        int h = i * 64 + lane;
        acc += qrow[h] * wrow[h];
    }
    #pragma unroll
    for (int m = 1; m < 64; m <<= 1) acc += __shfl_xor(acc, m);
    if (lane == 0) qbuf[b * H_ + o] = acc + Wa_b[o] + Ua_b[o];
}

// ---- kernel 1: fused k-proj MFMA + tanh + va-dot -> pscore[oh][b][l] (o-eighth partials)
__launch_bounds__(256, 3)
__global__ void score_kernel(const float* __restrict__ key, const ushort* __restrict__ Ufrag,
                             const float* __restrict__ qbuf, const float* __restrict__ va_w,
                             float* __restrict__ pscore) {
    // A chunk: [sl 0..3][m 0..3][lf 0..63][8] = 16 KB per buffer
    __shared__ ushort Alds[2][4 * 4 * 64 * 8];
    __shared__ float s_part[4][64];

    // sibling swizzle: 8 oh-blocks of one key l-tile share d%8 -> same XCD.
    int d    = blockIdx.x;                 // 4096 = 512 tiles * 8 oh
    int oh   = (d >> 3) & 7;
    int tile = (d & 7) | ((d >> 6) << 3);  // 0..511 = 32 b * 16 lt
    int b  = tile >> 4;
    int l0 = (tile & 15) * 128;
    int tid = threadIdx.x;                 // 256
    int w = tid >> 6, lane = tid & 63;
    int wm = w >> 1, wn = w & 1;

    // A staging coords: row r = tid>>1 (0..127), col half c0 = (tid&1)*32 (32 floats)
    int r    = tid >> 1;
    int c0   = (tid & 1) * 32;
    int mst  = r >> 5;
    int rr   = r & 31;
    const float* krow = key + ((size_t)b * L_ + (l0 + r)) * H_;

    int nb0 = oh * 4 + wn * 2;             // wave's 2 o-blocks (64 cols)
    const ushort* Uw = Ufrag + ((size_t)nb0 * 64 + lane) * 8;

    // ---- prologue: stage chunk 0 into buf 0; preload B s=0,1,2
    f32x4 ld[8];
    #pragma unroll
    for (int i = 0; i < 8; ++i) ld[i] = *(const f32x4*)(krow + c0 + 4 * i);
    bf16x8 bb[4][2];
    #pragma unroll
    for (int k = 0; k < 3; ++k)
        #pragma unroll
        for (int ni = 0; ni < 2; ++ni)
            bb[k][ni] = *(const bf16x8*)(Uw + (size_t)k * 16384 + ni * 512);
    #pragma unroll
    for (int e = 0; e < 4; ++e) {
        int hh = c0 + e * 8;
        int sl = hh >> 4;
        int lf = ((hh >> 3) & 1) * 32 + rr;
        uint4 pk;
        pk.x = pk_bf16(ld[2*e].x,   ld[2*e].y);
        pk.y = pk_bf16(ld[2*e].z,   ld[2*e].w);
        pk.z = pk_bf16(ld[2*e+1].x, ld[2*e+1].y);
        pk.w = pk_bf16(ld[2*e+1].z, ld[2*e+1].w);
        *(uint4*)&Alds[0][((sl * 4 + mst) * 64 + lf) * 8] = pk;
    }
    __syncthreads();

    f32x16 acc[2][2] = {};

    #pragma unroll 2
    for (int kc = 0; kc < 16; ++kc) {
        int cur = kc & 1;
        if (kc < 15) {
            // issue A loads for chunk kc+1 (land under this chunk's MFMAs)
            #pragma unroll
            for (int i = 0; i < 8; ++i)
                ld[i] = *(const f32x4*)(krow + (kc + 1) * 64 + c0 + 4 * i);
        }
        __builtin_amdgcn_s_setprio(1);
        #pragma unroll
        for (int sl = 0; sl < 4; ++sl) {
            int gs = kc * 4 + sl;
            bf16x8 a0 = *(const bf16x8*)&Alds[cur][((sl * 4 + wm * 2 + 0) * 64 + lane) * 8];
            bf16x8 a1 = *(const bf16x8*)&Alds[cur][((sl * 4 + wm * 2 + 1) * 64 + lane) * 8];
            int gp = (gs + 3) & 63;            // depth-3 B prefetch (tail wrap harmless)
            #pragma unroll
            for (int ni = 0; ni < 2; ++ni)
                bb[(gs + 3) & 3][ni] = *(const bf16x8*)(Uw + (size_t)gp * 16384 + ni * 512);
            acc[0][0] = __builtin_amdgcn_mfma_f32_32x32x16_bf16(a0, bb[gs & 3][0], acc[0][0], 0, 0, 0);
            acc[1][0] = __builtin_amdgcn_mfma_f32_32x32x16_bf16(a1, bb[gs & 3][0], acc[1][0], 0, 0, 0);
            acc[0][1] = __builtin_amdgcn_mfma_f32_32x32x16_bf16(a0, bb[gs & 3][1], acc[0][1], 0, 0, 0);
            acc[1][1] = __builtin_amdgcn_mfma_f32_32x32x16_bf16(a1, bb[gs & 3][1], acc[1][1], 0, 0, 0);
        }
        __builtin_amdgcn_s_setprio(0);
        if (kc < 15) {
            // convert + write chunk kc+1 into the DEAD buffer (cur^1) — no barrier needed
            // before these writes; the end-of-chunk barrier makes them visible.
            #pragma unroll
            for (int e = 0; e < 4; ++e) {
                int hh = c0 + e * 8;
                int sl = hh >> 4;
                int lf = ((hh >> 3) & 1) * 32 + rr;
                uint4 pk;
                pk.x = pk_bf16(ld[2*e].x,   ld[2*e].y);
                pk.y = pk_bf16(ld[2*e].z,   ld[2*e].w);
                pk.z = pk_bf16(ld[2*e+1].x, ld[2*e+1].y);
                pk.w = pk_bf16(ld[2*e+1].z, ld[2*e+1].w);
                *(uint4*)&Alds[cur ^ 1][((sl * 4 + mst) * 64 + lf) * 8] = pk;
            }
            __syncthreads();
        }
    }

    // ---- epilogue: rowsum over this wave's 64 o-cols
    // C/D: col=lane&31, row=(rg&3)+8*(rg>>2)+4*(lane>>5); wave rows = wm*64 + mi*32 + crow
    #pragma unroll
    for (int mi = 0; mi < 2; ++mi) {
        float rowsum[16];
        #pragma unroll
        for (int rg = 0; rg < 16; ++rg) rowsum[rg] = 0.f;
        #pragma unroll
        for (int ni = 0; ni < 2; ++ni) {
            int col = (nb0 + ni) * 32 + (lane & 31);
            float qv  = qbuf[b * H_ + col];
            float vav = va_w[col];
            #pragma unroll
            for (int rg = 0; rg < 16; ++rg)
                rowsum[rg] += vav * fast_tanh(qv + acc[mi][ni][rg]);
        }
        #pragma unroll
        for (int rg = 0; rg < 16; ++rg) {
            float v = rowsum[rg];
            v += __shfl_xor(v, 1);  v += __shfl_xor(v, 2);  v += __shfl_xor(v, 4);
            v += __shfl_xor(v, 8);  v += __shfl_xor(v, 16);
            if ((lane & 31) == 0) {
                int row = mi * 32 + (rg & 3) + 8 * (rg >> 2) + 4 * (lane >> 5);
                s_part[w][row] = v;   // block row = wm*64 + row
            }
        }
    }
    __syncthreads();
    if (tid < 128) {
        int wmf = tid >> 6;
        int r64 = tid & 63;
        float s = s_part[wmf * 2 + 0][r64] + s_part[wmf * 2 + 1][r64];
        pscore[((size_t)oh * B_ + b) * L_ + l0 + tid] = s;
    }
}

// ---- kernel 2: combine 8 o-eighth partials + bias + mask + softmax -> attn [B][L]
__global__ void softmax_kernel(const float* __restrict__ pscore, const float* __restrict__ va_b,
                               const int* __restrict__ mask, float* __restrict__ attn) {
    __shared__ float red[16];
    int b = blockIdx.x;
    int tid = threadIdx.x;    // 256
    float vab = va_b[0];
    float v[8];
    float mx = -3e38f;
    #pragma unroll
    for (int i = 0; i < 8; ++i) {
        int l = tid + i * 256;
        float s = vab;
        #pragma unroll
        for (int q = 0; q < 8; ++q) s += pscore[((size_t)q * B_ + b) * L_ + l];
        int m = mask[b * L_ + l];
        v[i] = (m == 0) ? -1e10f : s;
        mx = fmaxf(mx, v[i]);
    }
    #pragma unroll
    for (int m = 1; m < 64; m <<= 1) mx = fmaxf(mx, __shfl_xor(mx, m));
    if ((tid & 63) == 0) red[tid >> 6] = mx;
    __syncthreads();
    mx = fmaxf(fmaxf(red[0], red[1]), fmaxf(red[2], red[3]));
    float sum = 0.f;
    #pragma unroll
    for (int i = 0; i < 8; ++i) { v[i] = __expf(v[i] - mx); sum += v[i]; }
    #pragma unroll
    for (int m = 1; m < 64; m <<= 1) sum += __shfl_xor(sum, m);
    if ((tid & 63) == 0) red[8 + (tid >> 6)] = sum;
    __syncthreads();
    sum = red[8] + red[9] + red[10] + red[11];
    float inv = 1.f / sum;
    #pragma unroll
    for (int i = 0; i < 8; ++i) attn[b * L_ + tid + i * 256] = v[i] * inv;
}

// ---- kernel 3: partial context over 128-l chunks -> partial[b*16+ch][1024]
__global__ void context_kernel(const float* __restrict__ attn, const float* __restrict__ value,
                               float* __restrict__ partial) {
    int bid = blockIdx.x;            // 512 = 32 b * 16 chunks
    int b = bid >> 4, ch = bid & 15;
    int l0 = ch * 128;
    int tid = threadIdx.x;           // 256
    f32x4 acc = {0.f, 0.f, 0.f, 0.f};
    const float* vbase = value + ((size_t)b * L_ + l0) * H_ + tid * 4;
    const float* arow  = attn + b * L_ + l0;
    for (int l = 0; l < 128; ++l) {
        float a = arow[l];
        f32x4 vv = *(const f32x4*)(vbase + (size_t)l * H_);
        acc.x += a * vv.x; acc.y += a * vv.y; acc.z += a * vv.z; acc.w += a * vv.w;
    }
    *(f32x4*)(partial + (size_t)bid * H_ + tid * 4) = acc;
}

// ---- kernel 4: reduce 16 partials -> out [B][1][H]
__global__ void reduce_kernel(const float* __restrict__ partial, float* __restrict__ out) {
    int t = blockIdx.x * 256 + threadIdx.x;   // 32768
    int b = t >> 10, h = t & 1023;
    float s = 0.f;
    #pragma unroll
    for (int c = 0; c < 16; ++c) s += partial[(size_t)(b * 16 + c) * H_ + h];
    out[t] = s;
}

extern "C" void kernel_launch(void* const* d_in, const int* in_sizes, int n_in,
                              void* d_out, int out_size, void* d_ws, size_t ws_size,
                              hipStream_t stream) {
    const float* query = (const float*)d_in[0];
    const float* key   = (const float*)d_in[1];
    const float* value = (const float*)d_in[2];
    const int*   mask  = (const int*)d_in[3];
    const float* Wa_w  = (const float*)d_in[4];
    const float* Wa_b  = (const float*)d_in[5];
    const float* Ua_w  = (const float*)d_in[6];
    const float* Ua_b  = (const float*)d_in[7];
    const float* va_w  = (const float*)d_in[8];
    const float* va_b  = (const float*)d_in[9];
    float* out = (float*)d_out;

    char* ws = (char*)d_ws;
    ushort* Ufrag    = (ushort*)ws;                                   // 2 MB
    float*  qbuf     = (float*)(ws + (2u << 20));                     // 128 KB
    float*  pscore   = (float*)(ws + (2u << 20) + (128u << 10));      // 2 MB (8 eighths)
    float*  attnb    = (float*)(ws + (4u << 20) + (128u << 10));      // 256 KB
    float*  partial  = (float*)(ws + (4u << 20) + (384u << 10));      // 2 MB

    hipLaunchKernelGGL(prep_ua,        dim3(512),  dim3(256), 0, stream, Ua_w, Ufrag);
    hipLaunchKernelGGL(prep_q,         dim3(8192), dim3(256), 0, stream, query, Wa_w, Wa_b, Ua_b, qbuf);
    hipLaunchKernelGGL(score_kernel,   dim3(4096), dim3(256), 0, stream, key, Ufrag, qbuf, va_w, pscore);
    hipLaunchKernelGGL(softmax_kernel, dim3(32),   dim3(256), 0, stream, pscore, va_b, mask, attnb);
    hipLaunchKernelGGL(context_kernel, dim3(512),  dim3(256), 0, stream, attnb, value, partial);
    hipLaunchKernelGGL(reduce_kernel,  dim3(128),  dim3(256), 0, stream, partial, out);
}

// Round 10
// 275.395 us; speedup vs baseline: 1.4413x; 1.4413x over previous
//
#include <hip/hip_runtime.h>
#include <hip/hip_bf16.h>

// Bahdanau additive attention, B=32, L=2048, H=1024, fp32 in/out.
// score_kernel v5: R4 geometry (block = 64l x ALL 1024o, single-reader key, nt loads,
// K chunked 256 + LDS dbuf, depth-2 B reg-prefetch) but 1024-thread blocks:
// 16 waves x (64l x 64o), acc[2][2] = 64 AGPR, target 4 waves/SIMD (launch_bounds 1024,4).

#define B_ 32
#define L_ 2048
#define H_ 1024

typedef __attribute__((ext_vector_type(8))) short bf16x8;   // 8 bf16 = 4 VGPRs
typedef __attribute__((ext_vector_type(16))) float f32x16;  // 32x32 MFMA acc
typedef __attribute__((ext_vector_type(4))) float f32x4;

__device__ inline unsigned pk_bf16(float a, float b) {
    unsigned r;
    asm("v_cvt_pk_bf16_f32 %0, %1, %2" : "=v"(r) : "v"(a), "v"(b));
    return r;
}

__device__ inline float fast_tanh(float x) {
    float e = __expf(2.f * x);
    return 1.f - 2.f * __builtin_amdgcn_rcpf(e + 1.f);
}

__device__ inline f32x4 ntload4(const float* p) {
    // streaming (evict-first) so the 2MB Ufrag stays L2-resident
    return __builtin_nontemporal_load((const f32x4*)p);
}

// A-frag slot (ushort index): [s 0..15][m 0..1][lf 0..63][8], write/read XOR lf^(s&7)
__device__ inline int aslot(int s, int m, int lf) {
    return (((s * 2 + m) * 64) + (lf ^ (s & 7))) * 8;
}

// ---- kernel 0a: Ua_w -> bf16 B-fragments [s 0..63][nb 0..31][lane][j 0..7]
// lane l holds B[k=(l>>5)*8+j][col=nb*32+(l&31)], h = s*16+k.
__global__ void prep_ua(const float* __restrict__ Ua, ushort* __restrict__ Ufrag) {
    int t = blockIdx.x * 256 + threadIdx.x;   // 131072 slots of 8 ushort
    int lane = t & 63;
    int nb   = (t >> 6) & 31;
    int s    = t >> 11;
    int o = nb * 32 + (lane & 31);
    int h = s * 16 + (lane >> 5) * 8;
    const float* src = Ua + o * H_ + h;
    f32x4 f0 = *(const f32x4*)(src);
    f32x4 f1 = *(const f32x4*)(src + 4);
    uint4 pk;
    pk.x = pk_bf16(f0.x, f0.y);
    pk.y = pk_bf16(f0.z, f0.w);
    pk.z = pk_bf16(f1.x, f1.y);
    pk.w = pk_bf16(f1.z, f1.w);
    *(uint4*)(Ufrag + (size_t)t * 8) = pk;
}

// ---- kernel 0b: qbuf[b][o] = query[b]·Wa_w[o] + Wa_b[o] + Ua_b[o]
__global__ void prep_q(const float* __restrict__ query, const float* __restrict__ Wa_w,
                       const float* __restrict__ Wa_b, const float* __restrict__ Ua_b,
                       float* __restrict__ qbuf) {
    int wid  = blockIdx.x * 4 + (threadIdx.x >> 6);
    int lane = threadIdx.x & 63;
    int b = wid >> 10, o = wid & 1023;
    const float* qrow = query + b * H_;
    const float* wrow = Wa_w + o * H_;
    float acc = 0.f;
    #pragma unroll
    for (int i = 0; i < 16; ++i) {
        int h = i * 64 + lane;
        acc += qrow[h] * wrow[h];
    }
    #pragma unroll
    for (int m = 1; m < 64; m <<= 1) acc += __shfl_xor(acc, m);
    if (lane == 0) qbuf[b * H_ + o] = acc + Wa_b[o] + Ua_b[o];
}

// ---- kernel 1: fused k-proj MFMA + tanh + va-dot + mask -> scorebuf [B][L]
__launch_bounds__(1024, 4)
__global__ void score_kernel(const float* __restrict__ key, const ushort* __restrict__ Ufrag,
                             const float* __restrict__ qbuf, const float* __restrict__ va_w,
                             const float* __restrict__ va_b, const int* __restrict__ mask,
                             float* __restrict__ scorebuf) {
    __shared__ ushort Alds[2][16384];   // 2 x 32 KB (16 s x 2 m x 64 lf x 8)
    __shared__ float s_part[16][64];

    int bid = blockIdx.x;               // 1024 = 32 b * 32 l-tiles
    int b = bid >> 5, lt = bid & 31;
    int l0 = lt * 64;
    int tid = threadIdx.x;              // 1024
    int w = tid >> 6, lane = tid & 63;  // 16 waves

    // staging coords: row r = tid>>4 (0..63), 16 cols at c0 = (tid&15)*16 (one s-step)
    int r    = tid >> 4;
    int c0s  = tid & 15;                // chunk-relative s index
    int c0   = c0s * 16;
    int mblk = r >> 5;
    int rr   = r & 31;
    const float* krow = key + ((size_t)b * L_ + (l0 + r)) * H_;

    int nb0 = w * 2;                    // wave's 2 o-blocks (64 cols)
    const ushort* Uw = Ufrag + ((size_t)nb0 * 64 + lane) * 8;

    // ---- prologue: stage chunk 0; preload B s=0,1
    f32x4 ld[4];
    #pragma unroll
    for (int i = 0; i < 4; ++i) ld[i] = ntload4(krow + c0 + 4 * i);
    bf16x8 bc[2], b1[2];
    #pragma unroll
    for (int ni = 0; ni < 2; ++ni) {
        bc[ni] = *(const bf16x8*)(Uw + ni * 512);
        b1[ni] = *(const bf16x8*)(Uw + (size_t)16384 + ni * 512);
    }
    {
        uint4 pk0, pk1;
        pk0.x = pk_bf16(ld[0].x, ld[0].y);
        pk0.y = pk_bf16(ld[0].z, ld[0].w);
        pk0.z = pk_bf16(ld[1].x, ld[1].y);
        pk0.w = pk_bf16(ld[1].z, ld[1].w);
        pk1.x = pk_bf16(ld[2].x, ld[2].y);
        pk1.y = pk_bf16(ld[2].z, ld[2].w);
        pk1.z = pk_bf16(ld[3].x, ld[3].y);
        pk1.w = pk_bf16(ld[3].z, ld[3].w);
        *(uint4*)&Alds[0][aslot(c0s, mblk, rr)]      = pk0;   // k 0..7
        *(uint4*)&Alds[0][aslot(c0s, mblk, 32 + rr)] = pk1;   // k 8..15
    }
    __syncthreads();

    f32x16 acc[2][2] = {};

    for (int kc = 0; kc < 4; ++kc) {
        int cur = kc & 1;
        if (kc < 3) {
            // issue A loads for chunk kc+1 early (land under this chunk's MFMAs)
            #pragma unroll
            for (int i = 0; i < 4; ++i)
                ld[i] = ntload4(krow + (kc + 1) * 256 + c0 + 4 * i);
        }
        #pragma unroll 4
        for (int s = 0; s < 16; ++s) {
            bf16x8 a0 = *(const bf16x8*)&Alds[cur][aslot(s, 0, lane)];
            bf16x8 a1 = *(const bf16x8*)&Alds[cur][aslot(s, 1, lane)];
            int gp = (kc * 16 + s + 2) & 63;    // depth-2 B prefetch
            bf16x8 bn0 = *(const bf16x8*)(Uw + (size_t)gp * 16384);
            bf16x8 bn1 = *(const bf16x8*)(Uw + (size_t)gp * 16384 + 512);
            acc[0][0] = __builtin_amdgcn_mfma_f32_32x32x16_bf16(a0, bc[0], acc[0][0], 0, 0, 0);
            acc[1][0] = __builtin_amdgcn_mfma_f32_32x32x16_bf16(a1, bc[0], acc[1][0], 0, 0, 0);
            acc[0][1] = __builtin_amdgcn_mfma_f32_32x32x16_bf16(a0, bc[1], acc[0][1], 0, 0, 0);
            acc[1][1] = __builtin_amdgcn_mfma_f32_32x32x16_bf16(a1, bc[1], acc[1][1], 0, 0, 0);
            bc[0] = b1[0]; bc[1] = b1[1];
            b1[0] = bn0;   b1[1] = bn1;
        }
        if (kc < 3) {
            // convert + write chunk kc+1 into dead buffer; one barrier per chunk
            uint4 pk0, pk1;
            pk0.x = pk_bf16(ld[0].x, ld[0].y);
            pk0.y = pk_bf16(ld[0].z, ld[0].w);
            pk0.z = pk_bf16(ld[1].x, ld[1].y);
            pk0.w = pk_bf16(ld[1].z, ld[1].w);
            pk1.x = pk_bf16(ld[2].x, ld[2].y);
            pk1.y = pk_bf16(ld[2].z, ld[2].w);
            pk1.z = pk_bf16(ld[3].x, ld[3].y);
            pk1.w = pk_bf16(ld[3].z, ld[3].w);
            *(uint4*)&Alds[cur ^ 1][aslot(c0s, mblk, rr)]      = pk0;
            *(uint4*)&Alds[cur ^ 1][aslot(c0s, mblk, 32 + rr)] = pk1;
            __syncthreads();
        }
    }

    // ---- epilogue: rowsum = sum_o va[o]*tanh(q[o] + acc)
    // C/D: col=lane&31, row=(rg&3)+8*(rg>>2)+4*(lane>>5)
    #pragma unroll
    for (int mi = 0; mi < 2; ++mi) {
        float rowsum[16];
        #pragma unroll
        for (int rg = 0; rg < 16; ++rg) rowsum[rg] = 0.f;
        #pragma unroll
        for (int ni = 0; ni < 2; ++ni) {
            int col = w * 64 + ni * 32 + (lane & 31);
            float qv  = qbuf[b * H_ + col];
            float vav = va_w[col];
            #pragma unroll
            for (int rg = 0; rg < 16; ++rg)
                rowsum[rg] += vav * fast_tanh(qv + acc[mi][ni][rg]);
        }
        #pragma unroll
        for (int rg = 0; rg < 16; ++rg) {
            float v = rowsum[rg];
            v += __shfl_xor(v, 1);  v += __shfl_xor(v, 2);  v += __shfl_xor(v, 4);
            v += __shfl_xor(v, 8);  v += __shfl_xor(v, 16);
            if ((lane & 31) == 0) {
                int row = mi * 32 + (rg & 3) + 8 * (rg >> 2) + 4 * (lane >> 5);
                s_part[w][row] = v;
            }
        }
    }
    __syncthreads();
    if (tid < 64) {
        float s = 0.f;
        #pragma unroll
        for (int ww = 0; ww < 16; ++ww) s += s_part[ww][tid];
        int l = l0 + tid;
        int m = mask[b * L_ + l];
        scorebuf[b * L_ + l] = (m == 0) ? -1e10f : (s + va_b[0]);
    }
}

// ---- kernel 2: masked softmax over L per batch -> attn [B][L]
__global__ void softmax_kernel(const float* __restrict__ scorebuf, float* __restrict__ attn) {
    __shared__ float red[16];
    int b = blockIdx.x;
    int tid = threadIdx.x;    // 256
    float v[8];
    float mx = -3e38f;
    #pragma unroll
    for (int i = 0; i < 8; ++i) {
        v[i] = scorebuf[b * L_ + tid + i * 256];
        mx = fmaxf(mx, v[i]);
    }
    #pragma unroll
    for (int m = 1; m < 64; m <<= 1) mx = fmaxf(mx, __shfl_xor(mx, m));
    if ((tid & 63) == 0) red[tid >> 6] = mx;
    __syncthreads();
    mx = fmaxf(fmaxf(red[0], red[1]), fmaxf(red[2], red[3]));
    float sum = 0.f;
    #pragma unroll
    for (int i = 0; i < 8; ++i) { v[i] = __expf(v[i] - mx); sum += v[i]; }
    #pragma unroll
    for (int m = 1; m < 64; m <<= 1) sum += __shfl_xor(sum, m);
    if ((tid & 63) == 0) red[8 + (tid >> 6)] = sum;
    __syncthreads();
    sum = red[8] + red[9] + red[10] + red[11];
    float inv = 1.f / sum;
    #pragma unroll
    for (int i = 0; i < 8; ++i) attn[b * L_ + tid + i * 256] = v[i] * inv;
}

// ---- kernel 3: partial context over 128-l chunks -> partial[b*16+ch][1024]
__global__ void context_kernel(const float* __restrict__ attn, const float* __restrict__ value,
                               float* __restrict__ partial) {
    int bid = blockIdx.x;            // 512 = 32 b * 16 chunks
    int b = bid >> 4, ch = bid & 15;
    int l0 = ch * 128;
    int tid = threadIdx.x;           // 256
    f32x4 acc = {0.f, 0.f, 0.f, 0.f};
    const float* vbase = value + ((size_t)b * L_ + l0) * H_ + tid * 4;
    const float* arow  = attn + b * L_ + l0;
    for (int l = 0; l < 128; ++l) {
        float a = arow[l];
        f32x4 vv = *(const f32x4*)(vbase + (size_t)l * H_);
        acc.x += a * vv.x; acc.y += a * vv.y; acc.z += a * vv.z; acc.w += a * vv.w;
    }
    *(f32x4*)(partial + (size_t)bid * H_ + tid * 4) = acc;
}

// ---- kernel 4: reduce 16 partials -> out [B][1][H]
__global__ void reduce_kernel(const float* __restrict__ partial, float* __restrict__ out) {
    int t = blockIdx.x * 256 + threadIdx.x;   // 32768
    int b = t >> 10, h = t & 1023;
    float s = 0.f;
    #pragma unroll
    for (int c = 0; c < 16; ++c) s += partial[(size_t)(b * 16 + c) * H_ + h];
    out[t] = s;
}

extern "C" void kernel_launch(void* const* d_in, const int* in_sizes, int n_in,
                              void* d_out, int out_size, void* d_ws, size_t ws_size,
                              hipStream_t stream) {
    const float* query = (const float*)d_in[0];
    const float* key   = (const float*)d_in[1];
    const float* value = (const float*)d_in[2];
    const int*   mask  = (const int*)d_in[3];
    const float* Wa_w  = (const float*)d_in[4];
    const float* Wa_b  = (const float*)d_in[5];
    const float* Ua_w  = (const float*)d_in[6];
    const float* Ua_b  = (const float*)d_in[7];
    const float* va_w  = (const float*)d_in[8];
    const float* va_b  = (const float*)d_in[9];
    float* out = (float*)d_out;

    char* ws = (char*)d_ws;
    ushort* Ufrag    = (ushort*)ws;                                   // 2 MB
    float*  qbuf     = (float*)(ws + (2u << 20));                     // 128 KB
    float*  scorebuf = (float*)(ws + (2u << 20) + (128u << 10));      // 256 KB
    float*  attnb    = (float*)(ws + (2u << 20) + (384u << 10));      // 256 KB
    float*  partial  = (float*)(ws + (2u << 20) + (640u << 10));      // 2 MB

    hipLaunchKernelGGL(prep_ua,        dim3(512),  dim3(256),  0, stream, Ua_w, Ufrag);
    hipLaunchKernelGGL(prep_q,         dim3(8192), dim3(256),  0, stream, query, Wa_w, Wa_b, Ua_b, qbuf);
    hipLaunchKernelGGL(score_kernel,   dim3(1024), dim3(1024), 0, stream, key, Ufrag, qbuf, va_w, va_b, mask, scorebuf);
    hipLaunchKernelGGL(softmax_kernel, dim3(32),   dim3(256),  0, stream, scorebuf, attnb);
    hipLaunchKernelGGL(context_kernel, dim3(512),  dim3(256),  0, stream, attnb, value, partial);
    hipLaunchKernelGGL(reduce_kernel,  dim3(128),  dim3(256),  0, stream, partial, out);
}